// Round 7
// baseline (361.071 us; speedup 1.0000x reference)
//
#include <hip/hip_runtime.h>
#include <hip/hip_bf16.h>
#include <cstdint>

using i32x4 = __attribute__((ext_vector_type(4))) int;

// Problem dims
#define BATCH   128
#define NPATCH  196
#define MTOT    25088   // 128*196, = 98*256 exactly
#define MT      98      // M-tiles of 256
#define DDIM    768
#define WCON    32
#define NCOLS   4096    // BATCH*WCON
#define BNC     128     // cols per chunk
#define NBN     32      // NCOLS/BNC
#define NT      12      // K-tiles of 64
#define NCHUNK  3136    // MT*NBN
#define NPBLK   512     // persistent blocks

// ws layout (bytes), each 256-aligned
#define PI8_OFF   0ull
#define PI8_BYTES ((size_t)MTOT*DDIM)
#define CI8_OFF   (PI8_OFF + PI8_BYTES)
#define CI8_BYTES (4096ull*DDIM)
#define SP_OFF    (CI8_OFF + CI8_BYTES)
#define SP_BYTES  ((size_t)MTOT*4)
#define SC_OFF    (SP_OFF + SP_BYTES)
#define SC_BYTES  (4096ull*4)
#define IMGN_OFF  (SC_OFF + SC_BYTES)
#define F_BYTES   (128ull*768*4)
#define TXTN_OFF  (IMGN_OFF + F_BYTES)
#define MAX_OFF   (TXTN_OFF + F_BYTES)
#define MAX_BYTES (128ull*4096*4)
#define ACC_OFF   (MAX_OFF + MAX_BYTES)
#define WS_NEED   (ACC_OFF + 256ull)

__device__ __forceinline__ void async_cp16(void* lds_p, const void* g) {
  __builtin_amdgcn_global_load_lds(
      (const __attribute__((address_space(1))) unsigned int*)g,
      (__attribute__((address_space(3))) unsigned int*)lds_p, 16, 0, 0);
}

__device__ __forceinline__ float neg_log_sigmoid(float x) {
  return (x > 0.f) ? log1pf(expf(-x)) : (log1pf(expf(x)) - x);
}

__device__ __forceinline__ int encf(float f) {
  int i = __float_as_int(f);
  return i >= 0 ? i : (i ^ 0x7FFFFFFF);
}
__device__ __forceinline__ float decf(int e) {
  return __int_as_float(e >= 0 ? e : (e ^ 0x7FFFFFFF));
}

template<int VM>
__device__ __forceinline__ void vmwait() {
  asm volatile("s_waitcnt vmcnt(%0)" :: "n"(VM) : "memory");
}
__device__ __forceinline__ void blockbar() {
  asm volatile("" ::: "memory");
  __builtin_amdgcn_s_barrier();
  asm volatile("" ::: "memory");
}

// ---------------- normalization kernels ----------------

__global__ void norm_f32_kernel(const float* __restrict__ in, float* __restrict__ out) {
  int row = blockIdx.x;
  int t = threadIdx.x; // 0..191
  const float4* ir = (const float4*)(in + (size_t)row * DDIM);
  float4 v = ir[t];
  float ss = v.x*v.x + v.y*v.y + v.z*v.z + v.w*v.w;
  __shared__ float sb[3];
  #pragma unroll
  for (int o = 32; o; o >>= 1) ss += __shfl_down(ss, o);
  if ((t & 63) == 0) sb[t >> 6] = ss;
  __syncthreads();
  float tot = sb[0] + sb[1] + sb[2];
  float scale = 1.0f / fmaxf(sqrtf(tot), 1e-12f);
  ((float4*)(out + (size_t)row * DDIM))[t] =
      make_float4(v.x*scale, v.y*scale, v.z*scale, v.w*scale);
}

// per-row: normalize + symmetric-absmax int8 quantization.
__global__ void norm_quant_i8(const float* __restrict__ in, char* __restrict__ out,
                              float* __restrict__ srow) {
  int row = blockIdx.x;
  int t = threadIdx.x; // 0..191
  const float4* ir = (const float4*)(in + (size_t)row * DDIM);
  float4 v = ir[t];
  float ss = v.x*v.x + v.y*v.y + v.z*v.z + v.w*v.w;
  float am = fmaxf(fmaxf(fabsf(v.x), fabsf(v.y)), fmaxf(fabsf(v.z), fabsf(v.w)));
  __shared__ float sbs[3], sba[3];
  #pragma unroll
  for (int o = 32; o; o >>= 1) {
    ss += __shfl_down(ss, o);
    am = fmaxf(am, __shfl_down(am, o));
  }
  if ((t & 63) == 0) { sbs[t >> 6] = ss; sba[t >> 6] = am; }
  __syncthreads();
  float tot = sbs[0] + sbs[1] + sbs[2];
  float amx = fmaxf(fmaxf(sba[0], sba[1]), fmaxf(sba[2], 1e-30f));
  float qs = 127.0f / amx;
  int qx = (int)rintf(v.x * qs), qy = (int)rintf(v.y * qs);
  int qz = (int)rintf(v.z * qs), qw = (int)rintf(v.w * qs);
  uint packed = (uint)(qx & 0xff) | ((uint)(qy & 0xff) << 8) |
                ((uint)(qz & 0xff) << 16) | ((uint)(qw & 0xff) << 24);
  ((uint*)(out + (size_t)row * DDIM))[t] = packed;
  if (t == 0) srow[row] = amx / (127.0f * fmaxf(sqrtf(tot), 1e-12f));
}

// ---------------- persistent RC GEMM (int8) + column max ----------------
// 512 persistent blocks, dynamic chunk counter. Chunk = 256 rows x 128 cols,
// 12 K-tiles of 64. 256 threads, 4 waves (2Mx2N), wave 128x64, acc 8x4 i32x4.
// 3 LDS buffers x 24KB. Register-double-buffered fragments: body(t) =
// {stage(t+2) | vmcnt(6) | bar | ds_reads(t+1)->set[(t+1)&1] + MFMA(t) on
// set[t&1] | bar}. Pipeline never drains across chunk boundaries.
__global__ __launch_bounds__(256, 2)
void rc_gemm_max_kernel(const char* __restrict__ patches,
                        const char* __restrict__ concepts,
                        const float* __restrict__ sp,
                        const float* __restrict__ sc,
                        int* __restrict__ ctr,
                        int* __restrict__ Max) {
  __shared__ __align__(16) char lds[3 * 24576];
  __shared__ float sp_lds[256];
  __shared__ float colmax[2][2][128];
  __shared__ int chunk_lds[2];

  const int tid = threadIdx.x;
  const int lane = tid & 63;
  const int wid = tid >> 6;
  const int wm = wid >> 1;   // 0..1
  const int wn = wid & 1;    // 0..1

  // ds_read base offsets (quad-XOR swizzle; slot invariant across frag idx)
  const int arow = wm*128 + (lane & 15);
  const int aslot = (lane >> 4) ^ (((lane & 15) >> 1) & 3);
  const int a_base = arow*64 + aslot*16;
  const int bcl = wn*64 + (lane & 15);
  const int b_base = 16384 + bcl*64 + aslot*16;
  // staging voffset (element==byte for i8); slot invariant across k2 chunks
  const int r0 = tid >> 2;
  const int q0 = (tid & 3) ^ ((r0 >> 1) & 3);
  const int svoff = r0*DDIM + q0*16;

  i32x4 acc[8][4];
  #pragma unroll
  for (int i = 0; i < 8; ++i)
    #pragma unroll
    for (int j = 0; j < 4; ++j) { i32x4 z = {0,0,0,0}; acc[i][j] = z; }

  i32x4 a0[8], b0[4], a1[8], b1[4];   // fragment double-buffer

  // fetch first two chunks
  if (tid == 0) {
    chunk_lds[0] = atomicAdd(ctr, 1);
    chunk_lds[1] = atomicAdd(ctr, 1);
  }
  __syncthreads();
  int cur = chunk_lds[0];
  int nxt = chunk_lds[1];
  if (cur >= NCHUNK) return;

  int cbn = cur / MT, cmt = cur - cbn * MT;
  const char* curA = patches  + (size_t)cmt * 256 * DDIM;
  const char* curB = concepts + (size_t)cbn * BNC * DDIM;
  int brow = cmt * 256, bcol = cbn * BNC;
  sp_lds[tid] = sp[brow + tid];

  auto stage = [&](const char* A, const char* B, int kcol, int bufi) {
    char* dst = lds + bufi * 24576;
    #pragma unroll
    for (int k2 = 0; k2 < 4; ++k2)
      async_cp16(dst + tid*16 + k2*4096, A + svoff + k2*(64*DDIM) + kcol);
    #pragma unroll
    for (int k2 = 0; k2 < 2; ++k2)
      async_cp16(dst + 16384 + tid*16 + k2*4096, B + svoff + k2*(64*DDIM) + kcol);
  };

#define READS(AF, BF, BUFI)                                                   \
  {                                                                           \
    const char* _p = lds + (BUFI) * 24576;                                    \
    _Pragma("unroll")                                                         \
    for (int _i = 0; _i < 8; ++_i)                                            \
      AF[_i] = *(const i32x4*)(_p + a_base + _i*1024);                        \
    _Pragma("unroll")                                                         \
    for (int _j = 0; _j < 4; ++_j)                                            \
      BF[_j] = *(const i32x4*)(_p + b_base + _j*1024);                        \
  }

#define MFMA32(AF, BF)                                                        \
  {                                                                           \
    __builtin_amdgcn_s_setprio(1);                                            \
    _Pragma("unroll")                                                         \
    for (int _i = 0; _i < 8; ++_i)                                            \
      _Pragma("unroll")                                                       \
      for (int _j = 0; _j < 4; ++_j)                                          \
        acc[_i][_j] = __builtin_amdgcn_mfma_i32_16x16x64_i8(AF[_i], BF[_j],   \
                                                            acc[_i][_j], 0,0,0); \
    __builtin_amdgcn_s_setprio(0);                                            \
  }

// body for t=0..9 (stages cur tile t+2), compile-time T
#define BODY(T, AC, BC, AR, BR)                                               \
  {                                                                           \
    stage(curA, curB, ((T)+2)*64, ((T)+2)%3);                                 \
    vmwait<6>();                                                              \
    blockbar();                                                               \
    READS(AR, BR, ((T)+1)%3)                                                  \
    MFMA32(AC, BC)                                                            \
    blockbar();                                                               \
  }

  // prologue: stage cur tiles 0,1; read frags(0) into set0
  stage(curA, curB, 0, 0);
  stage(curA, curB, 64, 1);
  vmwait<6>();
  blockbar();
  READS(a0, b0, 0)

  for (;;) {
    const bool have_next = (nxt < NCHUNK);
    int nbn = 0, nmt = 0;
    const char *nA = curA, *nB = curB;
    if (have_next) {
      nbn = nxt / MT; nmt = nxt - nbn * MT;
      nA = patches  + (size_t)nmt * 256 * DDIM;
      nB = concepts + (size_t)nbn * BNC * DDIM;
    }
    if (tid == 0) chunk_lds[0] = have_next ? atomicAdd(ctr, 1) : NCHUNK;

    BODY(0, a0,b0, a1,b1)  BODY(1, a1,b1, a0,b0)
    BODY(2, a0,b0, a1,b1)  BODY(3, a1,b1, a0,b0)
    BODY(4, a0,b0, a1,b1)  BODY(5, a1,b1, a0,b0)
    BODY(6, a0,b0, a1,b1)  BODY(7, a1,b1, a0,b0)
    BODY(8, a0,b0, a1,b1)  BODY(9, a1,b1, a0,b0)

    if (have_next) {
      // t=10: stage next tile 0 -> buf0 ; t=11: stage next tile 1 -> buf1
      { stage(nA, nB, 0, 0); vmwait<6>(); blockbar();
        READS(a1, b1, 2) MFMA32(a0, b0) blockbar(); }
      { stage(nA, nB, 64, 1); vmwait<6>(); blockbar();
        READS(a0, b0, 0) MFMA32(a1, b1) blockbar(); }
    } else {
      // terminal chunk: no more staging; drain
      { vmwait<0>(); blockbar();
        READS(a1, b1, 2) MFMA32(a0, b0) blockbar(); }
      { blockbar();
        MFMA32(a1, b1) blockbar(); }
    }

    // ---- epilogue for cur: dequant + segmented column max ----
    {
      float cmax[4][2];
      #pragma unroll
      for (int j = 0; j < 4; ++j) { cmax[j][0] = -3e38f; cmax[j][1] = -3e38f; }
      float scv[4];
      #pragma unroll
      for (int j = 0; j < 4; ++j) scv[j] = sc[bcol + wn*64 + j*16 + (lane & 15)];
      const int img0w = (brow + wm*128) / NPATCH;
      #pragma unroll
      for (int i = 0; i < 8; ++i) {
        #pragma unroll
        for (int e = 0; e < 4; ++e) {
          int rl = wm*128 + i*16 + (lane >> 4)*4 + e;
          float spv = sp_lds[rl];
          int seg = ((brow + rl) / NPATCH) - img0w;   // 0 or 1
          #pragma unroll
          for (int j = 0; j < 4; ++j) {
            float v = (float)acc[i][j][e] * spv * scv[j];
            cmax[j][0] = (seg == 0) ? fmaxf(cmax[j][0], v) : cmax[j][0];
            cmax[j][1] = (seg == 1) ? fmaxf(cmax[j][1], v) : cmax[j][1];
          }
        }
      }
      #pragma unroll
      for (int j = 0; j < 4; ++j) {
        #pragma unroll
        for (int s = 0; s < 2; ++s) {
          float v = cmax[j][s];
          v = fmaxf(v, __shfl_xor(v, 16));
          v = fmaxf(v, __shfl_xor(v, 32));
          cmax[j][s] = v;
        }
      }
      if (lane < 16) {
        #pragma unroll
        for (int j = 0; j < 4; ++j) {
          colmax[wm][0][wn*64 + j*16 + lane] = cmax[j][0];
          colmax[wm][1][wn*64 + j*16 + lane] = cmax[j][1];
        }
      }
      __syncthreads();
      {
        int w = tid >> 7;
        int col = tid & 127;
        int i0 = (brow + w*128) / NPATCH;
        int i1 = (brow + w*128 + 127) / NPATCH;
        int gcol = bcol + col;
        atomicMax(&Max[(size_t)i0 * NCOLS + gcol], encf(colmax[w][0][col]));
        if (i1 != i0) atomicMax(&Max[(size_t)i1 * NCOLS + gcol], encf(colmax[w][1][col]));
      }
      // re-zero accumulators for next chunk
      #pragma unroll
      for (int i = 0; i < 8; ++i)
        #pragma unroll
        for (int j = 0; j < 4; ++j) { i32x4 z = {0,0,0,0}; acc[i][j] = z; }
    }

    if (!have_next) return;
    __syncthreads();            // colmax writes done; chunk_lds stable to read
    cur = nxt; curA = nA; curB = nB; brow = nmt * 256; bcol = nbn * BNC;
    nxt = chunk_lds[0];
    __syncthreads();            // all read chunk_lds before next loop-top write
    sp_lds[tid] = sp[brow + tid];
  }
#undef BODY
#undef MFMA32
#undef READS
}

// ---------------- losses ----------------

__global__ void it_loss_kernel(const float* __restrict__ imgn, const float* __restrict__ txtn,
                               const float* __restrict__ sc, const float* __restrict__ bi,
                               float* __restrict__ acc) {
  int m = blockIdx.x;
  int c = threadIdx.x;  // 128 threads
  __shared__ __align__(16) float arow[DDIM];
  for (int k = c; k < DDIM; k += 128) arow[k] = imgn[(size_t)m * DDIM + k];
  __syncthreads();
  const float4* br = (const float4*)(txtn + (size_t)c * DDIM);
  const float4* ar = (const float4*)arow;
  float dot = 0.f;
  #pragma unroll 8
  for (int k = 0; k < DDIM/4; ++k) {
    float4 x = ar[k], y = br[k];
    dot += x.x*y.x + x.y*y.y + x.z*y.z + x.w*y.w;
  }
  float t = expf(fminf(fmaxf(sc[0], -10.f), 10.f));
  float logit = fminf(fmaxf(t*dot + bi[0], -50.f), 50.f);
  float x = (c == m) ? logit : -logit;
  float v = neg_log_sigmoid(x);
  __shared__ float sb[2];
  #pragma unroll
  for (int o = 32; o; o >>= 1) v += __shfl_down(v, o);
  if ((c & 63) == 0) sb[c >> 6] = v;
  __syncthreads();
  if (c == 0) atomicAdd(acc, sb[0] + sb[1]);
}

__global__ void rc_loss_kernel(const int* __restrict__ Max, const int* __restrict__ counts,
                               const float* __restrict__ sc, const float* __restrict__ bi,
                               float* __restrict__ acc) {
  int m = blockIdx.x;
  int v = threadIdx.x;  // 128 threads
  const int* row = Max + (size_t)m * NCOLS + (size_t)v * WCON;
  int cnt = counts[v];
  float s = 0.f;
  for (int w = 0; w < cnt; ++w) s += decf(row[w]);
  float S = s / (float)cnt;
  float t = expf(fminf(fmaxf(sc[0], -10.f), 10.f));
  float logit = fminf(fmaxf(t*S + bi[0], -50.f), 50.f);
  float x = (v == m) ? logit : -logit;
  float val = neg_log_sigmoid(x);
  __shared__ float sb[2];
  #pragma unroll
  for (int o = 32; o; o >>= 1) val += __shfl_down(val, o);
  if ((v & 63) == 0) sb[v >> 6] = val;
  __syncthreads();
  if (v == 0) atomicAdd(acc, sb[0] + sb[1]);
}

__global__ void finalize_kernel(const float* __restrict__ acc, float* __restrict__ out) {
  if (threadIdx.x == 0 && blockIdx.x == 0) {
    float it = acc[0] * (1.f / 16384.f);
    float rc = acc[1] * (1.f / 16384.f);
    out[0] = it + 0.5f * rc;
    out[1] = it;
    out[2] = rc;
  }
}

// ---------------- launch ----------------

extern "C" void kernel_launch(void* const* d_in, const int* in_sizes, int n_in,
                              void* d_out, int out_size, void* d_ws, size_t ws_size,
                              hipStream_t stream) {
  const float* image_features        = (const float*)d_in[0];
  const float* text_features         = (const float*)d_in[1];
  const float* image_token_features  = (const float*)d_in[2];
  const float* concept_text_features = (const float*)d_in[3];
  const int*   concept_counts        = (const int*)d_in[4];
  const float* logit_scale           = (const float*)d_in[5];
  const float* logit_bias            = (const float*)d_in[6];
  float* out = (float*)d_out;

  if (ws_size < WS_NEED) {
    hipMemsetAsync(d_out, 0, (size_t)out_size * sizeof(float), stream);
    return;
  }

  char* ws = (char*)d_ws;
  char*  patches_i8  = ws + PI8_OFF;
  char*  concepts_i8 = ws + CI8_OFF;
  float* sp          = (float*)(ws + SP_OFF);
  float* scq         = (float*)(ws + SC_OFF);
  float* imgn        = (float*)(ws + IMGN_OFF);
  float* txtn        = (float*)(ws + TXTN_OFF);
  int*   Maxbuf      = (int*)(ws + MAX_OFF);
  float* acc         = (float*)(ws + ACC_OFF);          // [0]=it, [1]=rc
  int*   ctr         = (int*)(ws + ACC_OFF + 64);

  hipMemsetAsync(ws + ACC_OFF, 0, 256, stream);         // zero acc + ctr
  hipMemsetAsync(Maxbuf, 0x80, MAX_BYTES, stream);      // decodes very negative

  norm_f32_kernel<<<BATCH, 192, 0, stream>>>(image_features, imgn);
  norm_f32_kernel<<<BATCH, 192, 0, stream>>>(text_features, txtn);
  norm_quant_i8<<<MTOT, 192, 0, stream>>>(image_token_features, patches_i8, sp);
  norm_quant_i8<<<NCOLS, 192, 0, stream>>>(concept_text_features, concepts_i8, scq);

  rc_gemm_max_kernel<<<NPBLK, 256, 0, stream>>>(patches_i8, concepts_i8, sp, scq, ctr, Maxbuf);

  it_loss_kernel<<<BATCH, 128, 0, stream>>>(imgn, txtn, logit_scale, logit_bias, acc);
  rc_loss_kernel<<<BATCH, 128, 0, stream>>>(Maxbuf, concept_counts, logit_scale, logit_bias, acc + 1);
  finalize_kernel<<<1, 64, 0, stream>>>(acc, out);
}